// Round 9
// baseline (515.509 us; speedup 1.0000x reference)
//
#include <hip/hip_runtime.h>
#include <hip/hip_bf16.h>
#include <hip/hip_cooperative_groups.h>

namespace cg = cooperative_groups;

typedef unsigned short ushort_t;
typedef __bf16 bf16x8 __attribute__((ext_vector_type(8)));
typedef float f32x4 __attribute__((ext_vector_type(4)));

typedef const void __attribute__((address_space(1)))* gas1_t;
typedef void __attribute__((address_space(3)))* las3_t;

#define L_SZ 2048
#define DI   2048
#define M_ROWS 4096
#define NC 32
#define TC 64

__device__ __forceinline__ float bf2f(ushort_t u){
  unsigned x = ((unsigned)u) << 16; float f; __builtin_memcpy(&f, &x, 4); return f;
}
__device__ __forceinline__ ushort_t f2bf(float f){
  __hip_bfloat16 h = __float2bfloat16(f);
  ushort_t u; __builtin_memcpy(&u, &h, 2); return u;
}
__device__ __forceinline__ float siluf(float x){ return x / (1.0f + __expf(-x)); }
__device__ __forceinline__ float softplusf(float x){
  return (x > 20.0f) ? x : log1pf(__expf(x));
}

// ---------------- fused prep: all weight transposes + x cast, ONE launch ----
__global__ __launch_bounds__(256) void k_prep(
    const float* __restrict__ W_in, const float* __restrict__ W_delta,
    const float* __restrict__ W_out, const float* __restrict__ W_B,
    const float* __restrict__ W_C, const float* __restrict__ x,
    ushort_t* __restrict__ W_inT, ushort_t* __restrict__ W_bigT,
    ushort_t* __restrict__ W_outT, ushort_t* __restrict__ xb)
{
  int t = blockIdx.x;
  if (t >= 10368){
    size_t i = (size_t)(t - 10368) * 256 + threadIdx.x;
    float4 v = *(const float4*)(x + i * 4);
    ushort_t o[4] = { f2bf(v.x), f2bf(v.y), f2bf(v.z), f2bf(v.w) };
    *(uint2*)(xb + i * 4) = *(const uint2*)o;
    return;
  }
  const float* in; ushort_t* out; int R, C, tx, ty;
  if (t < 4096)      { in=W_in;    out=W_inT;  R=1024; C=4096; tx = t & 127; ty = t >> 7; }
  else if (t < 8192) { t -= 4096;  in=W_delta; out=W_bigT; R=2048; C=2048; tx = t & 63; ty = t >> 6; }
  else if (t < 10240){ t -= 8192;  in=W_out;   out=W_outT; R=2048; C=1024; tx = t & 31; ty = t >> 5; }
  else if (t < 10304){ t -= 10240; in=W_B;  out=W_bigT + (size_t)2048*2048; R=2048; C=16; tx=0; ty=t; }
  else               { t -= 10304; in=W_C;  out=W_bigT + (size_t)2064*2048; R=2048; C=16; tx=0; ty=t; }
  __shared__ ushort_t tile[32][33];
  int c0 = tx * 32, r0 = ty * 32;
  int xx = threadIdx.x & 31, yy = threadIdx.x >> 5;
  #pragma unroll
  for (int i = 0; i < 32; i += 8){
    int r = r0 + yy + i, c = c0 + xx;
    if (r < R && c < C) tile[yy + i][xx] = f2bf(in[(size_t)r * C + c]);
  }
  __syncthreads();
  #pragma unroll
  for (int i = 0; i < 32; i += 8){
    int c = c0 + yy + i, r = r0 + xx;
    if (r < R && c < C) out[(size_t)c * R + r] = tile[xx][yy + i];
  }
}

// ---------------- main GEMM: C[M,N] = A[M,K] * Bt[N,K]^T ----------------
// R8 core (BK=128, two 64-k slabs, XOR-swizzled LDS, conflicts=0).
// EPI: 0=store fp32, 1=silu->bf16, 2=softplus(+bias)->bf16 dl with fused
// Bm/Cm columns at n in [2048,2080), discard n>=2080 (padded-N fusion;
// 33x32 grid has no lonely tail unlike R4/R5's 17x32).
template<int BM, int BN, int EPI>
__global__ __launch_bounds__(256) void k_gemm_bt(
    const ushort_t* __restrict__ A, int lda,
    const ushort_t* __restrict__ Bt, int ldb,
    void* __restrict__ Cout, int ldc,
    const float* __restrict__ bias,
    float* __restrict__ Bm, float* __restrict__ Cm, int K)
{
  constexpr int WM = BM/2, WN = BN/2;
  constexpr int MT = WM/16, NT = WN/16;
  constexpr int ACH = BM*16;                // 16B chunks of A (two 64-k slabs)
  constexpr int BCH = BN*16;
  constexpr int NISSUE = (ACH+BCH)/256;
  __shared__ __align__(16) char lds[(BM+BN)*256];
  char* ldsA = lds;
  char* ldsB = lds + BM*256;
  const int tid  = threadIdx.x;
  const int wave = tid >> 6, lane = tid & 63;
  const int quad = lane >> 4, l16 = lane & 15;
  const int m_blk = blockIdx.y * BM, n_blk = blockIdx.x * BN;
  const int wm = (wave >> 1) * WM, wn = (wave & 1) * WN;

  f32x4 acc[MT][NT] = {};

  const ushort_t* gptr[NISSUE];
  char* lptr[NISSUE];
  #pragma unroll
  for (int i = 0; i < NISSUE; i++){
    int g = tid + i*256;
    if (g < ACH){
      int sl = (g >= ACH/2) ? 1 : 0;
      int gl = g - sl*(ACH/2);
      int row = gl >> 3, c = gl & 7;
      gptr[i] = A + (size_t)(m_blk + row) * lda + sl*64 + ((c ^ (row & 7)) * 8);
    } else {
      int gb = g - ACH;
      int sl = (gb >= BCH/2) ? 1 : 0;
      int gl = gb - sl*(BCH/2);
      int row = gl >> 3, c = gl & 7;
      gptr[i] = Bt + (size_t)(n_blk + row) * ldb + sl*64 + ((c ^ (row & 7)) * 8);
    }
    lptr[i] = lds + (size_t)g*16;
  }

  const int xsw = (l16 & 7);

  for (int k0 = 0; k0 < K; k0 += 128){
    #pragma unroll
    for (int i = 0; i < NISSUE; i++)
      __builtin_amdgcn_global_load_lds((gas1_t)(const void*)(gptr[i] + k0), (las3_t)lptr[i], 16, 0, 0);
    __syncthreads();
    #pragma unroll
    for (int sl = 0; sl < 2; sl++){
      #pragma unroll
      for (int s = 0; s < 2; s++){
        const int xa = ((s*4 + quad) ^ xsw) * 16;
        bf16x8 af[MT], bfr[NT];
        #pragma unroll
        for (int i = 0; i < MT; i++)
          af[i]  = *(const bf16x8*)(ldsA + sl*(BM*128) + (wm + i * 16 + l16) * 128 + xa);
        #pragma unroll
        for (int i = 0; i < NT; i++)
          bfr[i] = *(const bf16x8*)(ldsB + sl*(BN*128) + (wn + i * 16 + l16) * 128 + xa);
        #pragma unroll
        for (int mt = 0; mt < MT; mt++)
          #pragma unroll
          for (int nt = 0; nt < NT; nt++)
            acc[mt][nt] = __builtin_amdgcn_mfma_f32_16x16x32_bf16(af[mt], bfr[nt], acc[mt][nt], 0, 0, 0);
      }
    }
    __syncthreads();
  }

  #pragma unroll
  for (int mt = 0; mt < MT; mt++){
    #pragma unroll
    for (int nt = 0; nt < NT; nt++){
      #pragma unroll
      for (int r = 0; r < 4; r++){
        int m = m_blk + wm + mt * 16 + quad * 4 + r;
        int n = n_blk + wn + nt * 16 + l16;
        float v = acc[mt][nt][r];
        if (EPI == 0){
          ((float*)Cout)[(size_t)m * ldc + n] = v;
        } else if (EPI == 1){
          ((__hip_bfloat16*)Cout)[(size_t)m * ldc + n] = __float2bfloat16(siluf(v));
        } else {
          if (n < 2048)      ((ushort_t*)Cout)[(size_t)m * ldc + n] = f2bf(softplusf(v + bias[n]));
          else if (n < 2064) Bm[(size_t)m * 16 + (n - 2048)] = v;
          else if (n < 2080) Cm[(size_t)m * 16 + (n - 2064)] = v;
          // n >= 2080: padding, discard
        }
      }
    }
  }
}

__device__ __forceinline__ void load_An(const float* A_log, int d, float* An){
  const float* ap = A_log + (size_t)d * 16;
  #pragma unroll
  for (int j = 0; j < 16; j += 4){
    float4 v = *(const float4*)(ap + j);
    An[j]   = -__expf(v.x);
    An[j+1] = -__expf(v.y);
    An[j+2] = -__expf(v.z);
    An[j+3] = -__expf(v.w);
  }
}

// ---------------- fused cooperative scan: pass1 + combine + pass2 ----------
// grid (16, 32): blockIdx.x = channel group (256 ch), blockIdx.y = chunk.
// 512 blocks x 4 waves, 8KB LDS -> all co-resident (cooperative launch).
__global__ __launch_bounds__(256) void k_scan_fused(
    const ushort_t* __restrict__ delta, const ushort_t* __restrict__ U,
    const float* __restrict__ Bm, const float* __restrict__ Cm,
    const float* __restrict__ A_log, const float* __restrict__ Dpar,
    float* __restrict__ q, float* __restrict__ S,
    float* __restrict__ hin, ushort_t* __restrict__ Y)
{
  cg::grid_group gg = cg::this_grid();
  __shared__ float ldsBC[TC * 16 * 2];
  const int tid = threadIdx.x;
  const int ch  = blockIdx.x * 256 + tid;
  const int b   = ch >> 11, d = ch & 2047;
  const int c   = blockIdx.y;
  const int t0  = c * TC;
  const size_t row0 = (size_t)b * L_SZ + t0;

  // ---- pass 1: chunk-local scan with h_in = 0 ----
  {
    int tt = tid >> 2, n4 = (tid & 3) * 4;
    *(float4*)&ldsBC[tt * 16 + n4] = *(const float4*)&Bm[((size_t)b * L_SZ + t0 + tt) * 16 + n4];
  }
  float An[16];
  load_An(A_log, d, An);
  __syncthreads();
  float h[16];
  #pragma unroll
  for (int j = 0; j < 16; j++) h[j] = 0.f;
  float Ssum = 0.f;
  for (int ti = 0; ti < TC; ++ti){
    size_t row = row0 + ti;
    float dlt = bf2f(delta[row * DI + d]);
    float uv  = bf2f(U[row * 4096 + d]);
    float du  = dlt * uv;
    Ssum += dlt;
    #pragma unroll
    for (int nn = 0; nn < 16; nn++){
      float dA = __expf(dlt * An[nn]);
      h[nn] = fmaf(dA, h[nn], du * ldsBC[ti * 16 + nn]);
    }
  }
  size_t qb = ((size_t)c * M_ROWS + ch) * 16;
  #pragma unroll
  for (int j = 0; j < 16; j += 4)
    *(float4*)&q[qb + j] = make_float4(h[j], h[j+1], h[j+2], h[j+3]);
  S[(size_t)c * M_ROWS + ch] = Ssum;

  gg.sync();

  // ---- combine: sequential over chunks, 65536 workers (ch x n) ----
  {
    int g = (blockIdx.y * (int)gridDim.x + blockIdx.x) * 256 + tid;
    if (g < 65536){
      int ch2 = g >> 4, nn = g & 15, d2 = ch2 & 2047;
      float An2 = -__expf(A_log[(size_t)d2 * 16 + nn]);
      float hh = 0.f;
      for (int cc = 0; cc < NC; cc++){
        size_t base = (size_t)cc * M_ROWS + ch2;
        hin[base * 16 + nn] = hh;
        hh = fmaf(__expf(An2 * S[base]), hh, q[base * 16 + nn]);
      }
    }
  }

  gg.sync();

  // ---- pass 2: replay with h_in, emit y ----
  {
    int tt = tid >> 2, n4 = (tid & 3) * 4;
    size_t gb = ((size_t)b * L_SZ + t0 + tt) * 16 + n4;
    float4 bv = *(const float4*)&Bm[gb];
    float4 cv = *(const float4*)&Cm[gb];
    float2* dst = (float2*)&ldsBC[(tt * 16 + n4) * 2];
    dst[0] = make_float2(bv.x, cv.x);
    dst[1] = make_float2(bv.y, cv.y);
    dst[2] = make_float2(bv.z, cv.z);
    dst[3] = make_float2(bv.w, cv.w);
  }
  float Dv = Dpar[d];
  __syncthreads();
  size_t hb = ((size_t)c * M_ROWS + ch) * 16;
  #pragma unroll
  for (int j = 0; j < 16; j += 4){
    float4 hv = *(const float4*)&hin[hb + j];
    h[j] = hv.x; h[j+1] = hv.y; h[j+2] = hv.z; h[j+3] = hv.w;
  }
  for (int ti = 0; ti < TC; ++ti){
    size_t row = row0 + ti;
    float dlt = bf2f(delta[row * DI + d]);
    float uv  = bf2f(U[row * 4096 + d]);
    float du  = dlt * uv;
    float y = 0.f;
    #pragma unroll
    for (int nn = 0; nn < 16; nn++){
      float2 bc = *(const float2*)&ldsBC[(ti * 16 + nn) * 2];
      float dA = __expf(dlt * An[nn]);
      h[nn] = fmaf(dA, h[nn], du * bc.x);
      y = fmaf(h[nn], bc.y, y);
    }
    float sres = bf2f(U[row * 4096 + 2048 + d]);
    y = (y + uv * Dv) * sres;
    Y[row * DI + d] = f2bf(y);
  }
}

extern "C" void kernel_launch(void* const* d_in, const int* in_sizes, int n_in,
                              void* d_out, int out_size, void* d_ws, size_t ws_size,
                              hipStream_t stream)
{
  const float* x       = (const float*)d_in[0];
  const float* W_in    = (const float*)d_in[1];
  const float* W_delta = (const float*)d_in[2];
  const float* b_delta = (const float*)d_in[3];
  const float* W_B     = (const float*)d_in[4];
  const float* W_C     = (const float*)d_in[5];
  const float* A_log   = (const float*)d_in[6];
  const float* D_par   = (const float*)d_in[7];
  const float* W_out   = (const float*)d_in[8];

  char* ws = (char*)d_ws;
  size_t off = 0;
  auto alloc = [&](size_t bytes){ char* p = ws + off; off += (bytes + 255) & ~(size_t)255; return p; };
  ushort_t* W_inT  = (ushort_t*)alloc((size_t)4096*1024*2);
  ushort_t* W_bigT = (ushort_t*)alloc((size_t)2176*2048*2);   // W_deltaT 0..2047, W_BT 2048.., W_CT 2064.., pad(poison ok) 2080..2111
  ushort_t* W_outT = (ushort_t*)alloc((size_t)1024*2048*2);
  ushort_t* xb     = (ushort_t*)alloc((size_t)4096*1024*2);
  ushort_t* U      = (ushort_t*)alloc((size_t)4096*4096*2);
  ushort_t* dl     = (ushort_t*)alloc((size_t)4096*2048*2);   // delta in bf16 now
  float*    Bm     = (float*)alloc((size_t)4096*16*4);
  float*    Cm     = (float*)alloc((size_t)4096*16*4);
  float*    qbuf   = (float*)alloc((size_t)NC*4096*16*4);
  float*    Sbuf   = (float*)alloc((size_t)NC*4096*4);
  float*    hin    = (float*)alloc((size_t)NC*4096*16*4);
  ushort_t* Y      = (ushort_t*)alloc((size_t)4096*2048*2);

  // 1) fused prep
  k_prep<<<dim3(14464),256,0,stream>>>(W_in, W_delta, W_out, W_B, W_C, x,
                                       W_inT, W_bigT, W_outT, xb);

  // 2) GEMM1: U = silu(x @ W_in)
  k_gemm_bt<128,64,1><<<dim3(64,32),256,0,stream>>>(xb, 1024, W_inT, 1024, U, 4096,
                                                    nullptr, nullptr, nullptr, 1024);

  // 3) GEMM2 (padded-N fusion): dl = softplus(u@W_delta+b) [bf16], Bm/Cm = u@[W_B|W_C]
  k_gemm_bt<128,64,2><<<dim3(33,32),256,0,stream>>>(U, 4096, W_bigT, 2048, dl, 2048,
                                                    b_delta, Bm, Cm, 2048);

  // 4) fused cooperative scan (pass1 + combine + pass2)
  {
    void* args[] = { (void*)&dl, (void*)&U, (void*)&Bm, (void*)&Cm,
                     (void*)&A_log, (void*)&D_par,
                     (void*)&qbuf, (void*)&Sbuf, (void*)&hin, (void*)&Y };
    hipLaunchCooperativeKernel((const void*)k_scan_fused, dim3(16,NC), dim3(256),
                               args, 0, stream);
  }

  // 5) GEMM3: out = Y @ W_out (fp32 output)
  k_gemm_bt<64,64,0><<<dim3(16,64),256,0,stream>>>(Y, 2048, W_outT, 2048, d_out, 1024,
                                                   nullptr, nullptr, nullptr, 2048);
}

// Round 10
// 358.962 us; speedup vs baseline: 1.4361x; 1.4361x over previous
//
#include <hip/hip_runtime.h>
#include <hip/hip_bf16.h>

typedef unsigned short ushort_t;
typedef __bf16 bf16x8 __attribute__((ext_vector_type(8)));
typedef float f32x4 __attribute__((ext_vector_type(4)));

typedef const void __attribute__((address_space(1)))* gas1_t;
typedef void __attribute__((address_space(3)))* las3_t;

#define L_SZ 2048
#define DI   2048
#define M_ROWS 4096
#define NC 64
#define TC 32

__device__ __forceinline__ float bf2f(ushort_t u){
  unsigned x = ((unsigned)u) << 16; float f; __builtin_memcpy(&f, &x, 4); return f;
}
__device__ __forceinline__ ushort_t f2bf(float f){
  __hip_bfloat16 h = __float2bfloat16(f);
  ushort_t u; __builtin_memcpy(&u, &h, 2); return u;
}
__device__ __forceinline__ float siluf(float x){ return x / (1.0f + __expf(-x)); }
__device__ __forceinline__ float softplusf(float x){
  return (x > 20.0f) ? x : log1pf(__expf(x));
}

// ---------------- fused prep: all weight transposes + x cast, ONE launch ----
__global__ __launch_bounds__(256) void k_prep(
    const float* __restrict__ W_in, const float* __restrict__ W_delta,
    const float* __restrict__ W_out, const float* __restrict__ W_B,
    const float* __restrict__ W_C, const float* __restrict__ x,
    ushort_t* __restrict__ W_inT, ushort_t* __restrict__ W_bigT,
    ushort_t* __restrict__ W_outT, ushort_t* __restrict__ xb)
{
  int t = blockIdx.x;
  if (t >= 10368){
    size_t i = (size_t)(t - 10368) * 256 + threadIdx.x;
    float4 v = *(const float4*)(x + i * 4);
    ushort_t o[4] = { f2bf(v.x), f2bf(v.y), f2bf(v.z), f2bf(v.w) };
    *(uint2*)(xb + i * 4) = *(const uint2*)o;
    return;
  }
  const float* in; ushort_t* out; int R, C, tx, ty;
  if (t < 4096)      { in=W_in;    out=W_inT;  R=1024; C=4096; tx = t & 127; ty = t >> 7; }
  else if (t < 8192) { t -= 4096;  in=W_delta; out=W_bigT; R=2048; C=2048; tx = t & 63; ty = t >> 6; }
  else if (t < 10240){ t -= 8192;  in=W_out;   out=W_outT; R=2048; C=1024; tx = t & 31; ty = t >> 5; }
  else if (t < 10304){ t -= 10240; in=W_B;  out=W_bigT + (size_t)2048*2048; R=2048; C=16; tx=0; ty=t; }
  else               { t -= 10304; in=W_C;  out=W_bigT + (size_t)2064*2048; R=2048; C=16; tx=0; ty=t; }
  __shared__ ushort_t tile[32][33];
  int c0 = tx * 32, r0 = ty * 32;
  int xx = threadIdx.x & 31, yy = threadIdx.x >> 5;
  #pragma unroll
  for (int i = 0; i < 32; i += 8){
    int r = r0 + yy + i, c = c0 + xx;
    if (r < R && c < C) tile[yy + i][xx] = f2bf(in[(size_t)r * C + c]);
  }
  __syncthreads();
  #pragma unroll
  for (int i = 0; i < 32; i += 8){
    int c = c0 + yy + i, r = r0 + xx;
    if (r < R && c < C) out[(size_t)c * R + r] = tile[xx][yy + i];
  }
}

// ---------------- main GEMM: C[M,N] = A[M,K] * Bt[N,K]^T ----------------
// R8 core (BK=128, two 64-k slabs, XOR-swizzled LDS, conflicts=0).
// EPI: 0=store fp32, 1=silu->bf16, 2=softplus(+bias)->bf16 dl with fused
// Bm/Cm columns at n in [2048,2080), discard n>=2080 (padded-N, 33x32 grid).
template<int BM, int BN, int EPI>
__global__ __launch_bounds__(256) void k_gemm_bt(
    const ushort_t* __restrict__ A, int lda,
    const ushort_t* __restrict__ Bt, int ldb,
    void* __restrict__ Cout, int ldc,
    const float* __restrict__ bias,
    float* __restrict__ Bm, float* __restrict__ Cm, int K)
{
  constexpr int WM = BM/2, WN = BN/2;
  constexpr int MT = WM/16, NT = WN/16;
  constexpr int ACH = BM*16;                // 16B chunks of A (two 64-k slabs)
  constexpr int BCH = BN*16;
  constexpr int NISSUE = (ACH+BCH)/256;
  __shared__ __align__(16) char lds[(BM+BN)*256];
  char* ldsA = lds;
  char* ldsB = lds + BM*256;
  const int tid  = threadIdx.x;
  const int wave = tid >> 6, lane = tid & 63;
  const int quad = lane >> 4, l16 = lane & 15;
  const int m_blk = blockIdx.y * BM, n_blk = blockIdx.x * BN;
  const int wm = (wave >> 1) * WM, wn = (wave & 1) * WN;

  f32x4 acc[MT][NT] = {};

  const ushort_t* gptr[NISSUE];
  char* lptr[NISSUE];
  #pragma unroll
  for (int i = 0; i < NISSUE; i++){
    int g = tid + i*256;
    if (g < ACH){
      int sl = (g >= ACH/2) ? 1 : 0;
      int gl = g - sl*(ACH/2);
      int row = gl >> 3, c = gl & 7;
      gptr[i] = A + (size_t)(m_blk + row) * lda + sl*64 + ((c ^ (row & 7)) * 8);
    } else {
      int gb = g - ACH;
      int sl = (gb >= BCH/2) ? 1 : 0;
      int gl = gb - sl*(BCH/2);
      int row = gl >> 3, c = gl & 7;
      gptr[i] = Bt + (size_t)(n_blk + row) * ldb + sl*64 + ((c ^ (row & 7)) * 8);
    }
    lptr[i] = lds + (size_t)g*16;
  }

  const int xsw = (l16 & 7);

  for (int k0 = 0; k0 < K; k0 += 128){
    #pragma unroll
    for (int i = 0; i < NISSUE; i++)
      __builtin_amdgcn_global_load_lds((gas1_t)(const void*)(gptr[i] + k0), (las3_t)lptr[i], 16, 0, 0);
    __syncthreads();
    #pragma unroll
    for (int sl = 0; sl < 2; sl++){
      #pragma unroll
      for (int s = 0; s < 2; s++){
        const int xa = ((s*4 + quad) ^ xsw) * 16;
        bf16x8 af[MT], bfr[NT];
        #pragma unroll
        for (int i = 0; i < MT; i++)
          af[i]  = *(const bf16x8*)(ldsA + sl*(BM*128) + (wm + i * 16 + l16) * 128 + xa);
        #pragma unroll
        for (int i = 0; i < NT; i++)
          bfr[i] = *(const bf16x8*)(ldsB + sl*(BN*128) + (wn + i * 16 + l16) * 128 + xa);
        #pragma unroll
        for (int mt = 0; mt < MT; mt++)
          #pragma unroll
          for (int nt = 0; nt < NT; nt++)
            acc[mt][nt] = __builtin_amdgcn_mfma_f32_16x16x32_bf16(af[mt], bfr[nt], acc[mt][nt], 0, 0, 0);
      }
    }
    __syncthreads();
  }

  #pragma unroll
  for (int mt = 0; mt < MT; mt++){
    #pragma unroll
    for (int nt = 0; nt < NT; nt++){
      #pragma unroll
      for (int r = 0; r < 4; r++){
        int m = m_blk + wm + mt * 16 + quad * 4 + r;
        int n = n_blk + wn + nt * 16 + l16;
        float v = acc[mt][nt][r];
        if (EPI == 0){
          ((float*)Cout)[(size_t)m * ldc + n] = v;
        } else if (EPI == 1){
          ((__hip_bfloat16*)Cout)[(size_t)m * ldc + n] = __float2bfloat16(siluf(v));
        } else {
          if (n < 2048)      ((ushort_t*)Cout)[(size_t)m * ldc + n] = f2bf(softplusf(v + bias[n]));
          else if (n < 2064) Bm[(size_t)m * 16 + (n - 2048)] = v;
          else if (n < 2080) Cm[(size_t)m * 16 + (n - 2064)] = v;
        }
      }
    }
  }
}

__device__ __forceinline__ void load_An(const float* A_log, int d, float* An){
  const float* ap = A_log + (size_t)d * 16;
  #pragma unroll
  for (int j = 0; j < 16; j += 4){
    float4 v = *(const float4*)(ap + j);
    An[j]   = -__expf(v.x);
    An[j+1] = -__expf(v.y);
    An[j+2] = -__expf(v.z);
    An[j+3] = -__expf(v.w);
  }
}

// ---------------- scan pass 1: per-chunk partials (h_in = 0) ----------------
// NC=64 chunks of TC=32 -> 1024 blocks (4/CU, 4 waves/SIMD) + unroll-4 load
// batching: the scan was measured latency-bound (R9: 421 GB/s, VALU 21%).
__global__ __launch_bounds__(256) void k_scan1(
    const ushort_t* __restrict__ delta, const ushort_t* __restrict__ U,
    const float* __restrict__ Bm, const float* __restrict__ A_log,
    float* __restrict__ q, float* __restrict__ S)
{
  __shared__ float ldsB[TC * 16];
  const int tid = threadIdx.x;
  const int ch  = blockIdx.x * 256 + tid;
  const int b   = ch >> 11, d = ch & 2047;
  const int c   = blockIdx.y;
  const int t0  = c * TC;
  if (tid < 128){
    int tt = tid >> 2, n4 = (tid & 3) * 4;
    *(float4*)&ldsB[tt * 16 + n4] = *(const float4*)&Bm[((size_t)b * L_SZ + t0 + tt) * 16 + n4];
  }
  float An[16];
  load_An(A_log, d, An);
  __syncthreads();
  float h[16];
  #pragma unroll
  for (int j = 0; j < 16; j++) h[j] = 0.f;
  float Ssum = 0.f;
  const size_t row0 = (size_t)b * L_SZ + t0;
  for (int ti = 0; ti < TC; ti += 4){
    float dlt[4], uv[4];
    #pragma unroll
    for (int k = 0; k < 4; k++){
      size_t row = row0 + ti + k;
      dlt[k] = bf2f(delta[row * DI + d]);
      uv[k]  = bf2f(U[row * 4096 + d]);
    }
    #pragma unroll
    for (int k = 0; k < 4; k++){
      float du = dlt[k] * uv[k];
      Ssum += dlt[k];
      #pragma unroll
      for (int nn = 0; nn < 16; nn++)
        h[nn] = fmaf(__expf(dlt[k] * An[nn]), h[nn], du * ldsB[(ti + k) * 16 + nn]);
    }
  }
  size_t qb = ((size_t)c * M_ROWS + ch) * 16;
  #pragma unroll
  for (int j = 0; j < 16; j += 4)
    *(float4*)&q[qb + j] = make_float4(h[j], h[j+1], h[j+2], h[j+3]);
  S[(size_t)c * M_ROWS + ch] = Ssum;
}

// ---------------- scan combine: sequential over chunks ----------------
__global__ __launch_bounds__(256) void k_scan_combine(
    const float* __restrict__ q, const float* __restrict__ S,
    const float* __restrict__ A_log, float* __restrict__ hin)
{
  int gid = blockIdx.x * 256 + threadIdx.x;      // 65536 = 4096 ch * 16 n
  int ch = gid >> 4, nn = gid & 15, d = ch & 2047;
  float An = -__expf(A_log[(size_t)d * 16 + nn]);
  float h = 0.f;
  for (int c = 0; c < NC; c++){
    size_t base = (size_t)c * M_ROWS + ch;
    hin[base * 16 + nn] = h;
    h = fmaf(__expf(An * S[base]), h, q[base * 16 + nn]);
  }
}

// ---------------- scan pass 2: replay with h_in, emit y ----------------
__global__ __launch_bounds__(256) void k_scan2(
    const ushort_t* __restrict__ delta, const ushort_t* __restrict__ U,
    const float* __restrict__ Bm, const float* __restrict__ Cm,
    const float* __restrict__ A_log, const float* __restrict__ Dpar,
    const float* __restrict__ hin, ushort_t* __restrict__ Y)
{
  __shared__ float ldsBC[TC * 16 * 2];
  const int tid = threadIdx.x;
  const int ch  = blockIdx.x * 256 + tid;
  const int b   = ch >> 11, d = ch & 2047;
  const int c   = blockIdx.y;
  const int t0  = c * TC;
  {
    int tt = tid >> 3, n2 = (tid & 7) * 2;
    size_t gb = ((size_t)b * L_SZ + t0 + tt) * 16 + n2;
    float2 bv = *(const float2*)&Bm[gb];
    float2 cv = *(const float2*)&Cm[gb];
    float2* dst = (float2*)&ldsBC[(tt * 16 + n2) * 2];
    dst[0] = make_float2(bv.x, cv.x);
    dst[1] = make_float2(bv.y, cv.y);
  }
  float An[16];
  load_An(A_log, d, An);
  float Dv = Dpar[d];
  __syncthreads();
  float h[16];
  size_t hb = ((size_t)c * M_ROWS + ch) * 16;
  #pragma unroll
  for (int j = 0; j < 16; j += 4){
    float4 hv = *(const float4*)&hin[hb + j];
    h[j] = hv.x; h[j+1] = hv.y; h[j+2] = hv.z; h[j+3] = hv.w;
  }
  const size_t row0 = (size_t)b * L_SZ + t0;
  for (int ti = 0; ti < TC; ti += 4){
    float dlt[4], uv[4], sres[4];
    #pragma unroll
    for (int k = 0; k < 4; k++){
      size_t row = row0 + ti + k;
      dlt[k]  = bf2f(delta[row * DI + d]);
      uv[k]   = bf2f(U[row * 4096 + d]);
      sres[k] = bf2f(U[row * 4096 + 2048 + d]);
    }
    ushort_t yo[4];
    #pragma unroll
    for (int k = 0; k < 4; k++){
      float du = dlt[k] * uv[k];
      float y = 0.f;
      #pragma unroll
      for (int nn = 0; nn < 16; nn++){
        float2 bc = *(const float2*)&ldsBC[((ti + k) * 16 + nn) * 2];
        h[nn] = fmaf(__expf(dlt[k] * An[nn]), h[nn], du * bc.x);
        y = fmaf(h[nn], bc.y, y);
      }
      yo[k] = f2bf((y + uv[k] * Dv) * sres[k]);
    }
    #pragma unroll
    for (int k = 0; k < 4; k++)
      Y[(row0 + ti + k) * DI + d] = yo[k];
  }
}

extern "C" void kernel_launch(void* const* d_in, const int* in_sizes, int n_in,
                              void* d_out, int out_size, void* d_ws, size_t ws_size,
                              hipStream_t stream)
{
  const float* x       = (const float*)d_in[0];
  const float* W_in    = (const float*)d_in[1];
  const float* W_delta = (const float*)d_in[2];
  const float* b_delta = (const float*)d_in[3];
  const float* W_B     = (const float*)d_in[4];
  const float* W_C     = (const float*)d_in[5];
  const float* A_log   = (const float*)d_in[6];
  const float* D_par   = (const float*)d_in[7];
  const float* W_out   = (const float*)d_in[8];

  char* ws = (char*)d_ws;
  size_t off = 0;
  auto alloc = [&](size_t bytes){ char* p = ws + off; off += (bytes + 255) & ~(size_t)255; return p; };
  ushort_t* W_inT  = (ushort_t*)alloc((size_t)4096*1024*2);
  ushort_t* W_bigT = (ushort_t*)alloc((size_t)2176*2048*2);
  ushort_t* W_outT = (ushort_t*)alloc((size_t)1024*2048*2);
  ushort_t* xb     = (ushort_t*)alloc((size_t)4096*1024*2);
  ushort_t* U      = (ushort_t*)alloc((size_t)4096*4096*2);
  ushort_t* dl     = (ushort_t*)alloc((size_t)4096*2048*2);
  float*    Bm     = (float*)alloc((size_t)4096*16*4);
  float*    Cm     = (float*)alloc((size_t)4096*16*4);
  float*    qbuf   = (float*)alloc((size_t)NC*4096*16*4);
  float*    Sbuf   = (float*)alloc((size_t)NC*4096*4);
  float*    hin    = (float*)alloc((size_t)NC*4096*16*4);
  ushort_t* Y      = (ushort_t*)alloc((size_t)4096*2048*2);

  // 1) fused prep
  k_prep<<<dim3(14464),256,0,stream>>>(W_in, W_delta, W_out, W_B, W_C, x,
                                       W_inT, W_bigT, W_outT, xb);

  // 2) GEMM1: U = silu(x @ W_in)
  k_gemm_bt<128,64,1><<<dim3(64,32),256,0,stream>>>(xb, 1024, W_inT, 1024, U, 4096,
                                                    nullptr, nullptr, nullptr, 1024);

  // 3) GEMM2 (padded-N fusion): dl = softplus(u@W_delta+b) [bf16], Bm/Cm = u@[W_B|W_C]
  k_gemm_bt<128,64,2><<<dim3(33,32),256,0,stream>>>(U, 4096, W_bigT, 2048, dl, 2048,
                                                    b_delta, Bm, Cm, 2048);

  // 4-6) chunked selective scan (split kernels; coop fusion regressed in R9)
  k_scan1<<<dim3(16,NC),256,0,stream>>>(dl, U, Bm, A_log, qbuf, Sbuf);
  k_scan_combine<<<dim3(256),256,0,stream>>>(qbuf, Sbuf, A_log, hin);
  k_scan2<<<dim3(16,NC),256,0,stream>>>(dl, U, Bm, Cm, A_log, D_par, hin, Y);

  // 7) GEMM3: out = Y @ W_out (fp32 output)
  k_gemm_bt<64,64,0><<<dim3(16,64),256,0,stream>>>(Y, 2048, W_outT, 2048, d_out, 1024,
                                                   nullptr, nullptr, nullptr, 2048);
}